// Round 6
// baseline (22630.029 us; speedup 1.0000x reference)
//
#include <hip/hip_runtime.h>
#include <hip/hip_bf16.h>
#include <math.h>

#define Bc 256
#define Tc 256
#define Hc 512
#define INc 5
#define BH (Bc * Hc)
#define NB 256     // grid blocks == CU count: all co-resident (1 block/CU)
#define NTHR 512   // 8 waves/block = 2/SIMD
#define GLP 17
#define MFMA __builtin_amdgcn_mfma_f32_16x16x32_bf16
#define DYN_LDS (131072 + 4 * 64 * GLP * 4 + 64 * 4 + 320 * 4)  // 150016 B

typedef __bf16 bf16x8 __attribute__((ext_vector_type(8)));
typedef float f32x4 __attribute__((ext_vector_type(4)));

__device__ __forceinline__ float sigmoidf_(float x) {
    return 1.0f / (1.0f + __expf(-x));
}
__device__ __forceinline__ float tanhf_(float x) {
    float ax = fabsf(x);
    float e = __expf(2.0f * ax);
    float t = 1.0f - 2.0f / (e + 1.0f);
    return copysignf(t, x);
}
__device__ __forceinline__ unsigned short bfbits(float x) {  // RNE f32->bf16 bits
    unsigned int u = __builtin_bit_cast(unsigned int, x);
    unsigned int r = u + 0x7FFFu + ((u >> 16) & 1u);
    return (unsigned short)(r >> 16);
}

// Monotonic grid barrier (proven R4/R5). NOTE: the agent-scope fence
// invalidates L1/L2 each step — that is WHY weights live in LDS (immune).
__device__ __forceinline__ void gbar(int* cnt, int gen, int tid) {
    __threadfence();
    __syncthreads();
    if (tid == 0) {
        __hip_atomic_fetch_add(cnt, 1, __ATOMIC_RELEASE, __HIP_MEMORY_SCOPE_AGENT);
        const int target = NB * gen;
        while (__hip_atomic_load(cnt, __ATOMIC_ACQUIRE, __HIP_MEMORY_SCOPE_AGENT) < target)
            __builtin_amdgcn_s_sleep(1);
    }
    __syncthreads();
}

// Blocks 0..127: layer0; 128..255: layer1 (K=1024: wcat1 = [w_hh1 | w_ih1]).
// Block (bb,jb): batch [bb*64,+64), j [jb*16,+16), all 4 gates.
// Wave wid: g = wid&3 (gate), mh = wid>>2 (m-half): 2 m-tiles of 16 batches.
// Weight slice lives in LDS (swizzled, 2-way max bank conflict on ds_read_b128).
__global__ void __launch_bounds__(NTHR, 1) lstm_persist(
    const float* __restrict__ x_time, const float* __restrict__ w_ih0,
    const float* __restrict__ b0v, const float* __restrict__ b1v,
    const float* __restrict__ fc1_w, const float* __restrict__ fc1_b,
    const float* __restrict__ x_stat,
    const float* __restrict__ fc2_w, const float* __restrict__ fc2_b,
    const float* __restrict__ fc3_w, const float* __restrict__ fc3_b,
    const __hip_bfloat16* __restrict__ wbf_hh0,
    const __hip_bfloat16* __restrict__ wcat1,
    __hip_bfloat16* h0, __hip_bfloat16* h1,
    float* __restrict__ partial, int* bar, float* __restrict__ out)
{
    extern __shared__ char smem[];                   // [0,131072): weights (swizzled)
    float* gl     = (float*)(smem + 131072);         // [4][64][GLP]
    float* bias_s = gl + 4 * 64 * GLP;               // [4][16]
    float* wih_s  = bias_s + 64;                     // [4][16][INc]

    const int layer = blockIdx.x >> 7;
    const int bid   = blockIdx.x & 127;
    const int bb = bid >> 5, jb = bid & 31;
    const int b0i = bb * 64, j0 = jb * 16;
    const int tid = threadIdx.x, lane = tid & 63;
    const int wid = tid >> 6, g = wid & 3, mh = wid >> 2;
    const int lrow = lane & 15, lgrp = lane >> 4;

    // ---- one-time staging (global -> LDS), then never touch weight globals ----
    {
        const float* bsrc = (layer == 0) ? b0v : b1v;
        if (tid < 64) bias_s[tid] = bsrc[(tid >> 4) * Hc + j0 + (tid & 15)];
        if (layer == 0 && tid < 320) {
            int gg = tid / 80, r = tid % 80, jl = r / INc, d = r % INc;
            wih_s[(gg * 16 + jl) * INc + d] = w_ih0[(size_t)(gg * Hc + j0 + jl) * INc + d];
        }
        if (layer == 0) {
#pragma unroll
            for (int it = 0; it < 8; it++) {         // 4096 x 16B = 64 KB
                int idx = it * NTHR + tid;
                int gg = idx >> 10, row = (idx >> 6) & 15, k8 = idx & 63;
                bf16x8 v = *reinterpret_cast<const bf16x8*>(
                    wbf_hh0 + (size_t)(gg * Hc + j0 + row) * Hc + k8 * 8);
                *reinterpret_cast<bf16x8*>(
                    smem + (gg * 16 + row) * 1024 + ((k8 * 16) ^ ((row & 7) << 4))) = v;
            }
        } else {
#pragma unroll
            for (int it = 0; it < 16; it++) {        // 8192 x 16B = 128 KB
                int idx = it * NTHR + tid;
                int gg = idx >> 11, row = (idx >> 7) & 15, k8 = idx & 127;
                bf16x8 v = *reinterpret_cast<const bf16x8*>(
                    wcat1 + (size_t)(gg * Hc + j0 + row) * 1024 + k8 * 8);
                *reinterpret_cast<bf16x8*>(
                    smem + (gg * 16 + row) * 2048 + ((k8 * 16) ^ ((row & 7) << 4))) = v;
            }
        }
    }
    __syncthreads();

    const int bl = tid >> 3, j4 = tid & 7;           // epilogue: (batch 0..63, j-pair 0..7)
    const int b = b0i + bl;
    const int arow0 = b0i + (mh * 2) * 16 + lrow;    // first m-tile A row
    const int ksw = (lrow & 7) << 4;
    float c_r[2] = {0.f, 0.f};

    if (layer == 0) {
        const int wbase = (g * 16 + lrow) * 1024;
        for (int i = 0; i <= Tc; i++) {
            if (i < Tc) {
                const __hip_bfloat16* h0r = h0 + (size_t)(i & 1) * BH;
                __hip_bfloat16* h0w = h0 + (size_t)((i & 1) ^ 1) * BH;
                float xv[INc];
#pragma unroll
                for (int d = 0; d < INc; d++)
                    xv[d] = x_time[((size_t)b * Tc + i) * INc + d];

                f32x4 acc0 = {0.f,0.f,0.f,0.f}, acc1 = {0.f,0.f,0.f,0.f};
                const __hip_bfloat16* pa = h0r + (size_t)arow0 * Hc + lgrp * 8;
#pragma unroll
                for (int kc = 0; kc < 16; kc++) {
                    bf16x8 A0 = *reinterpret_cast<const bf16x8*>(pa + kc * 32);
                    bf16x8 A1 = *reinterpret_cast<const bf16x8*>(pa + 16 * Hc + kc * 32);
                    bf16x8 Bv = *reinterpret_cast<const bf16x8*>(
                        smem + wbase + ((kc * 64 + lgrp * 16) ^ ksw));
                    acc0 = MFMA(A0, Bv, acc0, 0, 0, 0);
                    acc1 = MFMA(A1, Bv, acc1, 0, 0, 0);
                }
                const int mrow = (mh * 2) * 16 + lgrp * 4;
#pragma unroll
                for (int r = 0; r < 4; r++) {
                    gl[(g * 64 + mrow + r) * GLP + lrow]      = acc0[r];
                    gl[(g * 64 + mrow + 16 + r) * GLP + lrow] = acc1[r];
                }
                __syncthreads();

                unsigned int pk = 0;
#pragma unroll
                for (int jj = 0; jj < 2; jj++) {
                    const int jl = j4 * 2 + jj;
                    float pre[4];
#pragma unroll
                    for (int gg = 0; gg < 4; gg++) {
                        float s = gl[(gg * 64 + bl) * GLP + jl] + bias_s[gg * 16 + jl];
#pragma unroll
                        for (int d = 0; d < INc; d++)
                            s = fmaf(xv[d], wih_s[(gg * 16 + jl) * INc + d], s);
                        pre[gg] = s;
                    }
                    float ig = sigmoidf_(pre[0]), fg = sigmoidf_(pre[1]);
                    float gv = tanhf_(pre[2]), og = sigmoidf_(pre[3]);
                    float c = fg * c_r[jj] + ig * gv;
                    c_r[jj] = c;
                    float h = og * tanhf_(c);
                    pk |= (unsigned int)bfbits(h) << (16 * jj);
                }
                *reinterpret_cast<unsigned int*>(h0w + (size_t)b * Hc + j0 + j4 * 2) = pk;
            }
            gbar(bar, i + 1, tid);
        }
        gbar(bar, Tc + 2, tid);
        if (blockIdx.x == 0 && tid < 256) {
            float t0s = fc1_b[0], t1s = fc1_b[1];
            for (int jg = 0; jg < 32; jg++) {
                t0s += partial[((size_t)jg * Bc + tid) * 2 + 0];
                t1s += partial[((size_t)jg * Bc + tid) * 2 + 1];
            }
            float s0 = fc2_b[0] + x_stat[tid * 3 + 0] * fc2_w[0] + x_stat[tid * 3 + 1] * fc2_w[1] + x_stat[tid * 3 + 2] * fc2_w[2];
            float s1 = fc2_b[1] + x_stat[tid * 3 + 0] * fc2_w[3] + x_stat[tid * 3 + 1] * fc2_w[4] + x_stat[tid * 3 + 2] * fc2_w[5];
            out[tid * 2 + 0] = fc3_b[0] + fc3_w[0] * s0 + fc3_w[1] * s1 + fc3_w[2] * t0s + fc3_w[3] * t1s;
            out[tid * 2 + 1] = fc3_b[1] + fc3_w[4] * s0 + fc3_w[5] * s1 + fc3_w[6] * t0s + fc3_w[7] * t1s;
        }
    } else {
        const int wbase = (g * 16 + lrow) * 2048;
        float v0 = 0.f, v1 = 0.f;
        for (int i = 0; i <= Tc; i++) {
            if (i >= 1) {
                const int t1 = i - 1;
                const __hip_bfloat16* h1r = h1 + (size_t)((i & 1) ^ 1) * BH;
                __hip_bfloat16* h1w = h1 + (size_t)(i & 1) * BH;
                const __hip_bfloat16* h0r = h0 + (size_t)(i & 1) * BH;
                float wf0[2], wf1[2];
                {
                    const float* fp = fc1_w + (size_t)t1 * Hc + j0 + j4 * 2;
#pragma unroll
                    for (int jj = 0; jj < 2; jj++) {
                        wf0[jj] = fp[jj];
                        wf1[jj] = fp[(size_t)Tc * Hc + jj];
                    }
                }
                f32x4 acc0 = {0.f,0.f,0.f,0.f}, acc1 = {0.f,0.f,0.f,0.f};
                const __hip_bfloat16* pa1 = h1r + (size_t)arow0 * Hc + lgrp * 8;
                const __hip_bfloat16* pa0 = h0r + (size_t)arow0 * Hc + lgrp * 8;
#pragma unroll
                for (int kc = 0; kc < 32; kc++) {
                    const __hip_bfloat16* p = (kc < 16) ? (pa1 + kc * 32) : (pa0 + (kc - 16) * 32);
                    bf16x8 A0 = *reinterpret_cast<const bf16x8*>(p);
                    bf16x8 A1 = *reinterpret_cast<const bf16x8*>(p + 16 * Hc);
                    bf16x8 Bv = *reinterpret_cast<const bf16x8*>(
                        smem + wbase + ((kc * 64 + lgrp * 16) ^ ksw));
                    acc0 = MFMA(A0, Bv, acc0, 0, 0, 0);
                    acc1 = MFMA(A1, Bv, acc1, 0, 0, 0);
                }
                const int mrow = (mh * 2) * 16 + lgrp * 4;
#pragma unroll
                for (int r = 0; r < 4; r++) {
                    gl[(g * 64 + mrow + r) * GLP + lrow]      = acc0[r];
                    gl[(g * 64 + mrow + 16 + r) * GLP + lrow] = acc1[r];
                }
                __syncthreads();

                unsigned int pk = 0;
#pragma unroll
                for (int jj = 0; jj < 2; jj++) {
                    const int jl = j4 * 2 + jj;
                    float pre[4];
#pragma unroll
                    for (int gg = 0; gg < 4; gg++)
                        pre[gg] = gl[(gg * 64 + bl) * GLP + jl] + bias_s[gg * 16 + jl];
                    float ig = sigmoidf_(pre[0]), fg = sigmoidf_(pre[1]);
                    float gv = tanhf_(pre[2]), og = sigmoidf_(pre[3]);
                    float c = fg * c_r[jj] + ig * gv;
                    c_r[jj] = c;
                    float h = og * tanhf_(c);
                    v0 = fmaf(h, wf0[jj], v0);
                    v1 = fmaf(h, wf1[jj], v1);
                    pk |= (unsigned int)bfbits(h) << (16 * jj);
                }
                *reinterpret_cast<unsigned int*>(h1w + (size_t)b * Hc + j0 + j4 * 2) = pk;
            }
            gbar(bar, i + 1, tid);
        }
        // fc1 partial: reduce 8 j4-lanes -> 16 j's per (jb,b), write once
#pragma unroll
        for (int off = 1; off < 8; off <<= 1) {
            v0 += __shfl_xor(v0, off);
            v1 += __shfl_xor(v1, off);
        }
        if (j4 == 0) {
            partial[((size_t)jb * Bc + b) * 2 + 0] = v0;
            partial[((size_t)jb * Bc + b) * 2 + 1] = v1;
        }
        gbar(bar, Tc + 2, tid);
    }
}

__global__ void convert_weights(const float* __restrict__ w_hh0,
                                const float* __restrict__ w_hh1,
                                const float* __restrict__ w_ih1,
                                __hip_bfloat16* __restrict__ o_hh0,
                                __hip_bfloat16* __restrict__ o_cat)
{
    const int i = blockIdx.x * 256 + threadIdx.x;  // 4096*256 = 2048*512
    o_hh0[i] = __float2bfloat16(w_hh0[i]);
    const int r = i >> 9, k = i & 511;
    o_cat[(size_t)r * 1024 + k] = __float2bfloat16(w_hh1[i]);
    o_cat[(size_t)r * 1024 + 512 + k] = __float2bfloat16(w_ih1[i]);
}

extern "C" void kernel_launch(void* const* d_in, const int* in_sizes, int n_in,
                              void* d_out, int out_size, void* d_ws, size_t ws_size,
                              hipStream_t stream)
{
    const float* x_time = (const float*)d_in[0];
    const float* x_stat = (const float*)d_in[1];
    const float* w_ih0 = (const float*)d_in[2];
    const float* w_hh0 = (const float*)d_in[3];
    const float* b0    = (const float*)d_in[4];
    const float* w_ih1 = (const float*)d_in[5];
    const float* w_hh1 = (const float*)d_in[6];
    const float* b1    = (const float*)d_in[7];
    const float* fc1_w = (const float*)d_in[8];
    const float* fc1_b = (const float*)d_in[9];
    const float* fc2_w = (const float*)d_in[10];
    const float* fc2_b = (const float*)d_in[11];
    const float* fc3_w = (const float*)d_in[12];
    const float* fc3_b = (const float*)d_in[13];

    __hip_bfloat16* wbf_hh0 = (__hip_bfloat16*)d_ws;                 // 2048*512
    __hip_bfloat16* wcat1 = wbf_hh0 + (size_t)2048 * 512;            // 2048*1024
    __hip_bfloat16* h0p = wcat1 + (size_t)2048 * 1024;               // 2*BH
    __hip_bfloat16* h1p = h0p + (size_t)2 * BH;                      // 2*BH
    float* partialp = (float*)(h1p + (size_t)2 * BH);                // 32*256*2
    int* barp = (int*)(partialp + (size_t)32 * Bc * 2);

    // zero h0,h1 (bf16), partial, barrier counter
    const size_t zoff = ((size_t)2048 * 512 + (size_t)2048 * 1024) * sizeof(__hip_bfloat16);
    const size_t zlen = (size_t)4 * BH * sizeof(__hip_bfloat16)
                      + (size_t)32 * Bc * 2 * sizeof(float) + 256;
    hipMemsetAsync((char*)d_ws + zoff, 0, zlen, stream);

    convert_weights<<<4096, 256, 0, stream>>>(w_hh0, w_hh1, w_ih1, wbf_hh0, wcat1);

    static int lds_set = 0;
    if (!lds_set) {   // host-side attribute, not a stream op; idempotent
        hipFuncSetAttribute((const void*)lstm_persist,
                            hipFuncAttributeMaxDynamicSharedMemorySize, DYN_LDS);
        lds_set = 1;
    }
    lstm_persist<<<NB, NTHR, DYN_LDS, stream>>>(
        x_time, w_ih0, b0, b1, fc1_w, fc1_b, x_stat,
        fc2_w, fc2_b, fc3_w, fc3_b,
        wbf_hh0, wcat1, h0p, h1p, partialp, barp, (float*)d_out);
}

// Round 7
// 6429.699 us; speedup vs baseline: 3.5196x; 3.5196x over previous
//
#include <hip/hip_runtime.h>
#include <hip/hip_bf16.h>
#include <math.h>

#define Bc 256
#define Tc 256
#define Hc 512
#define INc 5
#define BH (Bc * Hc)
#define MFMA __builtin_amdgcn_mfma_f32_16x16x32_bf16

typedef __bf16 bf16x8 __attribute__((ext_vector_type(8)));
typedef float f32x4 __attribute__((ext_vector_type(4)));

__device__ __forceinline__ float sigmoidf_(float x) {
    return 1.0f / (1.0f + __expf(-x));
}
__device__ __forceinline__ float tanhf_(float x) {
    float ax = fabsf(x);
    float e = __expf(2.0f * ax);
    float t = 1.0f - 2.0f / (e + 1.0f);
    return copysignf(t, x);
}
__device__ __forceinline__ unsigned short bfbits(float x) {  // RNE f32->bf16 bits
    unsigned int u = __builtin_bit_cast(unsigned int, x);
    unsigned int r = u + 0x7FFFu + ((u >> 16) & 1u);
    return (unsigned short)(r >> 16);
}

// Per-step kernel, NO grid barrier (launch boundary = sync; L2 stays warm for
// read-only weights). 512 blocks x 512 thr = 2 blocks/CU, up to 4 waves/SIMD.
// Blocks 0..255: layer0 step t0. 256..511: layer1 step t1 = t0-1.
// Block (bb 0..7, jb 0..31): batches [bb*32,+32), j [jb*16,+16), 4 gates.
// Wave (g = wid&3, mh = wid>>2): gate g, m-tile mh -> one 16x16 MFMA output.
// Weight-slice-sharing blocks (same jb) have bid = jb + 32k -> same XCD (mod 8).
__global__ __launch_bounds__(512, 4) void lstm_step(
    const float* __restrict__ x_time, const float* __restrict__ b0v,
    const float* __restrict__ b1v, const float* __restrict__ fc1_w,
    const float* __restrict__ w_ih0,
    const __hip_bfloat16* __restrict__ wbf_hh0,
    const __hip_bfloat16* __restrict__ wcat1,
    const __hip_bfloat16* __restrict__ h0r, __hip_bfloat16* __restrict__ h0w,
    float* __restrict__ c0,
    const __hip_bfloat16* __restrict__ h1r, __hip_bfloat16* __restrict__ h1w,
    float* __restrict__ c1,
    float* __restrict__ partial,
    int t0, int t1, int l0, int l1)
{
    const int layer = blockIdx.x >> 8;
    if (layer == 0 && !l0) return;
    if (layer == 1 && !l1) return;
    const int bid = blockIdx.x & 255;
    const int bb = bid >> 5, jb = bid & 31;
    const int b0i = bb * 32, j0 = jb * 16;
    const int tid = threadIdx.x, lane = tid & 63;
    const int wid = tid >> 6, g = wid & 3, mh = wid >> 2;
    const int lrow = lane & 15, lgrp = lane >> 4;

    __shared__ float gl[4][32][17];
    __shared__ float bias_s[64];
    __shared__ float wih_s[320];

    if (tid < 64)
        bias_s[tid] = ((layer == 0) ? b0v : b1v)[(tid >> 4) * Hc + j0 + (tid & 15)];
    if (layer == 0 && tid < 320) {
        int gg = tid / 80, r = tid % 80, jl = r / INc, d = r % INc;
        wih_s[(gg * 16 + jl) * INc + d] = w_ih0[(size_t)(gg * Hc + j0 + jl) * INc + d];
    }

    // ---- MFMA: one 16x16 tile per wave ----
    const int arow = b0i + mh * 16 + lrow;   // A row (batch)
    f32x4 acc = {0.f, 0.f, 0.f, 0.f};
    if (layer == 0) {
        const __hip_bfloat16* pa = h0r + (size_t)arow * Hc + lgrp * 8;
        const __hip_bfloat16* pb = wbf_hh0 + (size_t)(g * Hc + j0 + lrow) * Hc + lgrp * 8;
#pragma unroll
        for (int kc = 0; kc < 16; kc++) {
            bf16x8 A = *reinterpret_cast<const bf16x8*>(pa + kc * 32);
            bf16x8 B = *reinterpret_cast<const bf16x8*>(pb + kc * 32);
            acc = MFMA(A, B, acc, 0, 0, 0);
        }
    } else {
        const __hip_bfloat16* pa1 = h1r + (size_t)arow * Hc + lgrp * 8;
        const __hip_bfloat16* pa0 = h0r + (size_t)arow * Hc + lgrp * 8;
        const __hip_bfloat16* pb = wcat1 + (size_t)(g * Hc + j0 + lrow) * 1024 + lgrp * 8;
#pragma unroll
        for (int kc = 0; kc < 16; kc++) {
            bf16x8 A = *reinterpret_cast<const bf16x8*>(pa1 + kc * 32);
            bf16x8 B = *reinterpret_cast<const bf16x8*>(pb + kc * 32);
            acc = MFMA(A, B, acc, 0, 0, 0);
        }
#pragma unroll
        for (int kc = 0; kc < 16; kc++) {
            bf16x8 A = *reinterpret_cast<const bf16x8*>(pa0 + kc * 32);
            bf16x8 B = *reinterpret_cast<const bf16x8*>(pb + 512 + kc * 32);
            acc = MFMA(A, B, acc, 0, 0, 0);
        }
    }
    // D layout: row = lgrp*4 + r, col = lrow
#pragma unroll
    for (int r = 0; r < 4; r++)
        gl[g][mh * 16 + lgrp * 4 + r][lrow] = acc[r];
    __syncthreads();

    // ---- epilogue: 1 (b, j) cell per thread ----
    const int bl = tid >> 4, jl = tid & 15;
    const int b = b0i + bl, j = j0 + jl;

    if (layer == 0) {
        float pre[4];
#pragma unroll
        for (int gg = 0; gg < 4; gg++)
            pre[gg] = gl[gg][bl][jl] + bias_s[gg * 16 + jl];
        const float* xp = x_time + ((size_t)b * Tc + t0) * INc;
#pragma unroll
        for (int d = 0; d < INc; d++) {
            float xv = xp[d];
#pragma unroll
            for (int gg = 0; gg < 4; gg++)
                pre[gg] = fmaf(xv, wih_s[(gg * 16 + jl) * INc + d], pre[gg]);
        }
        float ig = sigmoidf_(pre[0]), fg = sigmoidf_(pre[1]);
        float gv = tanhf_(pre[2]), og = sigmoidf_(pre[3]);
        float c = fg * c0[(size_t)b * Hc + j] + ig * gv;
        c0[(size_t)b * Hc + j] = c;
        h0w[(size_t)b * Hc + j] = __hip_bfloat16_raw{bfbits(og * tanhf_(c))};
    } else {
        float pre[4];
#pragma unroll
        for (int gg = 0; gg < 4; gg++)
            pre[gg] = gl[gg][bl][jl] + bias_s[gg * 16 + jl];
        float ig = sigmoidf_(pre[0]), fg = sigmoidf_(pre[1]);
        float gv = tanhf_(pre[2]), og = sigmoidf_(pre[3]);
        float c = fg * c1[(size_t)b * Hc + j] + ig * gv;
        c1[(size_t)b * Hc + j] = c;
        float h = og * tanhf_(c);
        h1w[(size_t)b * Hc + j] = __hip_bfloat16_raw{bfbits(h)};
        // fused fc1 partial
        float v0 = h * fc1_w[(size_t)t1 * Hc + j];
        float v1 = h * fc1_w[(size_t)Tc * Hc + (size_t)t1 * Hc + j];
#pragma unroll
        for (int off = 1; off < 16; off <<= 1) {
            v0 += __shfl_xor(v0, off);
            v1 += __shfl_xor(v1, off);
        }
        if (jl == 0) {
            float* p = &partial[((size_t)jb * Bc + b) * 2];
            p[0] += v0;
            p[1] += v1;
        }
    }
}

__global__ void convert_weights(const float* __restrict__ w_hh0,
                                const float* __restrict__ w_hh1,
                                const float* __restrict__ w_ih1,
                                __hip_bfloat16* __restrict__ o_hh0,
                                __hip_bfloat16* __restrict__ o_cat)
{
    const int i = blockIdx.x * 256 + threadIdx.x;  // 4096*256 = 2048*512
    o_hh0[i] = __float2bfloat16(w_hh0[i]);
    const int r = i >> 9, k = i & 511;
    o_cat[(size_t)r * 1024 + k] = __float2bfloat16(w_hh1[i]);
    o_cat[(size_t)r * 1024 + 512 + k] = __float2bfloat16(w_ih1[i]);
}

__global__ void finalize_kernel(const float* __restrict__ x_stat,
                                const float* __restrict__ fc1_b,
                                const float* __restrict__ fc2_w, const float* __restrict__ fc2_b,
                                const float* __restrict__ fc3_w, const float* __restrict__ fc3_b,
                                const float* __restrict__ partial, float* __restrict__ out)
{
    const int b = threadIdx.x;  // 256
    float t0 = fc1_b[0], t1 = fc1_b[1];
    for (int jg = 0; jg < 32; jg++) {
        t0 += partial[((size_t)jg * Bc + b) * 2 + 0];
        t1 += partial[((size_t)jg * Bc + b) * 2 + 1];
    }
    const float s0 = fc2_b[0] + x_stat[b * 3 + 0] * fc2_w[0] + x_stat[b * 3 + 1] * fc2_w[1] + x_stat[b * 3 + 2] * fc2_w[2];
    const float s1 = fc2_b[1] + x_stat[b * 3 + 0] * fc2_w[3] + x_stat[b * 3 + 1] * fc2_w[4] + x_stat[b * 3 + 2] * fc2_w[5];
    out[b * 2 + 0] = fc3_b[0] + fc3_w[0] * s0 + fc3_w[1] * s1 + fc3_w[2] * t0 + fc3_w[3] * t1;
    out[b * 2 + 1] = fc3_b[1] + fc3_w[4] * s0 + fc3_w[5] * s1 + fc3_w[6] * t0 + fc3_w[7] * t1;
}

extern "C" void kernel_launch(void* const* d_in, const int* in_sizes, int n_in,
                              void* d_out, int out_size, void* d_ws, size_t ws_size,
                              hipStream_t stream)
{
    const float* x_time = (const float*)d_in[0];
    const float* x_stat = (const float*)d_in[1];
    const float* w_ih0 = (const float*)d_in[2];
    const float* w_hh0 = (const float*)d_in[3];
    const float* b0    = (const float*)d_in[4];
    const float* w_ih1 = (const float*)d_in[5];
    const float* w_hh1 = (const float*)d_in[6];
    const float* b1    = (const float*)d_in[7];
    const float* fc1_w = (const float*)d_in[8];
    const float* fc1_b = (const float*)d_in[9];
    const float* fc2_w = (const float*)d_in[10];
    const float* fc2_b = (const float*)d_in[11];
    const float* fc3_w = (const float*)d_in[12];
    const float* fc3_b = (const float*)d_in[13];

    __hip_bfloat16* wbf_hh0 = (__hip_bfloat16*)d_ws;                 // 2048*512
    __hip_bfloat16* wcat1 = wbf_hh0 + (size_t)2048 * 512;            // 2048*1024
    __hip_bfloat16* h0p = wcat1 + (size_t)2048 * 1024;               // 2*BH
    __hip_bfloat16* h1p = h0p + (size_t)2 * BH;                      // 2*BH
    float* c0p = (float*)(h1p + (size_t)2 * BH);                     // BH f32
    float* c1p = c0p + (size_t)BH;                                   // BH f32
    float* partialp = c1p + (size_t)BH;                              // 32*256*2

    // zero h (1MB bf16), c (2MB f32), partial (64KB)
    const size_t zoff = ((size_t)2048 * 512 + (size_t)2048 * 1024) * sizeof(__hip_bfloat16);
    const size_t zlen = (size_t)4 * BH * sizeof(__hip_bfloat16)
                      + (size_t)2 * BH * sizeof(float)
                      + (size_t)32 * Bc * 2 * sizeof(float);
    hipMemsetAsync((char*)d_ws + zoff, 0, zlen, stream);

    convert_weights<<<4096, 256, 0, stream>>>(w_hh0, w_hh1, w_ih1, wbf_hh0, wcat1);

    for (int i = 0; i <= Tc; i++) {
        const int p = i & 1;
        const __hip_bfloat16* h0r = h0p + (size_t)p * BH;
        __hip_bfloat16* h0wp      = h0p + (size_t)(p ^ 1) * BH;
        const __hip_bfloat16* h1r = h1p + (size_t)(p ^ 1) * BH;
        __hip_bfloat16* h1wp      = h1p + (size_t)p * BH;
        lstm_step<<<512, 512, 0, stream>>>(
            x_time, b0, b1, fc1_w, w_ih0, wbf_hh0, wcat1,
            h0r, h0wp, c0p, h1r, h1wp, c1p, partialp,
            i, i - 1, (i < Tc) ? 1 : 0, (i >= 1) ? 1 : 0);
    }
    finalize_kernel<<<1, 256, 0, stream>>>(x_stat, fc1_b, fc2_w, fc2_b, fc3_w, fc3_b,
                                           partialp, (float*)d_out);
}